// Round 4
// baseline (59.624 us; speedup 1.0000x reference)
//
#include <hip/hip_runtime.h>

// Problem constants (match reference)
#define PNX 432
#define PNY 496
#define PNC 64
#define PLANE (PNY * PNX)   // 214272 = 837*256

typedef float f32x4 __attribute__((ext_vector_type(4)));

#define CSPLIT 2                 // channel slices (blockIdx.y)
#define CPERS (PNC / CSPLIT)     // 32 channels per slice
#define GPERS (CPERS / 4)        // 8 float4 groups per slice

// ---------------- map build ----------------

// Scatter pillar index p into map at its global cell. (map pre-set to -1
// via hipMemsetAsync 0xFF.)
__global__ void pp_scatter_map(const int4* __restrict__ coords,
                               int* __restrict__ map, int P) {
    int p = blockIdx.x * blockDim.x + threadIdx.x;
    if (p >= P) return;
    int4 c = coords[p];              // (b, z, y, x)
    int gidx = c.x * PLANE + c.y + c.z * PNX + c.w;
    map[gidx] = p;
}

// ---------------- gather ----------------
// Grid: (837, CSPLIT) x 256. Each thread: 4 consecutive cells x 32 channels.
// Feature rows loaded as 16B chunks; 4x4 register transpose; plain 16B
// stores (write-through L2, like the 6.8 TB/s fill kernel).
__global__ void pp_gather(const float* __restrict__ feat,
                          const int* __restrict__ map,
                          float* __restrict__ out, int n4) {
    int t = blockIdx.x * blockDim.x + threadIdx.x;   // cell4 index
    if (t >= n4) return;
    int cell0 = t * 4;
    int b = cell0 / PLANE;
    int spat = cell0 - b * PLANE;
    int cbase = blockIdx.y * CPERS;

    int4 pm = *reinterpret_cast<const int4*>(map + cell0);
    const f32x4* fp0 = reinterpret_cast<const f32x4*>(feat + (long)pm.x * PNC + cbase);
    const f32x4* fp1 = reinterpret_cast<const f32x4*>(feat + (long)pm.y * PNC + cbase);
    const f32x4* fp2 = reinterpret_cast<const f32x4*>(feat + (long)pm.z * PNC + cbase);
    const f32x4* fp3 = reinterpret_cast<const f32x4*>(feat + (long)pm.w * PNC + cbase);

    float* outp = out + (size_t)b * PNC * PLANE + (size_t)cbase * PLANE + spat;
    const f32x4 z = {0.f, 0.f, 0.f, 0.f};

    #pragma unroll
    for (int g = 0; g < GPERS; ++g) {                // 4 channels per group
        f32x4 r0 = (pm.x >= 0) ? fp0[g] : z;
        f32x4 r1 = (pm.y >= 0) ? fp1[g] : z;
        f32x4 r2 = (pm.z >= 0) ? fp2[g] : z;
        f32x4 r3 = (pm.w >= 0) ? fp3[g] : z;
        // transpose: output channel c holds (cell0..cell0+3)
        f32x4 o0 = {r0.x, r1.x, r2.x, r3.x};
        f32x4 o1 = {r0.y, r1.y, r2.y, r3.y};
        f32x4 o2 = {r0.z, r1.z, r2.z, r3.z};
        f32x4 o3 = {r0.w, r1.w, r2.w, r3.w};
        float* o = outp + (size_t)(g * 4) * PLANE;
        *reinterpret_cast<f32x4*>(o) = o0;
        *reinterpret_cast<f32x4*>(o + PLANE) = o1;
        *reinterpret_cast<f32x4*>(o + 2 * PLANE) = o2;
        *reinterpret_cast<f32x4*>(o + 3 * PLANE) = o3;
    }
}

// ---------------- fallback path (ws too small) ----------------

__global__ void pp_zero_out(f32x4* __restrict__ out4, size_t n4) {
    size_t t = (size_t)blockIdx.x * blockDim.x + threadIdx.x;
    size_t stride = (size_t)gridDim.x * blockDim.x;
    const f32x4 z = {0.f, 0.f, 0.f, 0.f};
    for (size_t i = t; i < n4; i += stride) out4[i] = z;
}

__global__ void pp_scatter_direct(const float* __restrict__ feat,
                                  const int4* __restrict__ coords,
                                  float* __restrict__ out, int P) {
    int t = blockIdx.x * blockDim.x + threadIdx.x;
    int p = t >> 6;
    int c = t & 63;
    if (p >= P) return;
    int4 co = coords[p];
    size_t oidx = ((size_t)(co.x * PNC + c)) * PLANE + co.y + co.z * PNX + co.w;
    out[oidx] = feat[p * PNC + c];
}

extern "C" void kernel_launch(void* const* d_in, const int* in_sizes, int n_in,
                              void* d_out, int out_size, void* d_ws, size_t ws_size,
                              hipStream_t stream) {
    const float* feat = (const float*)d_in[0];
    const int4* coords = (const int4*)d_in[1];
    float* out = (float*)d_out;

    const int P = in_sizes[0] / PNC;                 // 64000
    const int B = out_size / (PNC * PLANE);          // 4
    const int ncells = B * PLANE;                    // 857088
    const size_t mapBytes = (size_t)ncells * sizeof(int);

    if (ws_size >= mapBytes) {
        int* map = (int*)d_ws;
        int n4 = ncells / 4;                         // 214272
        // 1. map = -1 (0xFFFFFFFF) via the optimized rocclr fill
        (void)hipMemsetAsync(map, 0xFF, mapBytes, stream);
        // 2. scatter pillar ids into map
        pp_scatter_map<<<(P + 255) / 256, 256, 0, stream>>>(coords, map, P);
        // 3. gather: write every output element (coalesced float4)
        dim3 grid((n4 + 255) / 256, CSPLIT);
        pp_gather<<<grid, 256, 0, stream>>>(feat, map, out, n4);
    } else {
        // Fallback: zero-fill + direct scatter (correct but more HBM traffic)
        size_t n4 = (size_t)out_size / 4;
        pp_zero_out<<<2048, 256, 0, stream>>>((f32x4*)out, n4);
        int total = P * PNC;
        pp_scatter_direct<<<(total + 255) / 256, 256, 0, stream>>>(feat, coords, out, P);
    }
}

// Round 6
// 46.043 us; speedup vs baseline: 1.2950x; 1.2950x over previous
//
#include <hip/hip_runtime.h>

// Problem constants (match reference)
#define PNX 432
#define PNY 496
#define PNC 64
#define PLANE (PNY * PNX)   // 214272 = 837*256

typedef float f32x4 __attribute__((ext_vector_type(4)));

// ---------------- init: map = -1, zrow = 0 ----------------
// zrow is a 64-float zero feature row in ws; empty cells gather from it,
// making the gather kernel fully branch-free (no conditional loads).
__global__ void pp_init(int4* __restrict__ map4, float* __restrict__ zrow, int n4) {
    int t = blockIdx.x * blockDim.x + threadIdx.x;
    if (t < n4) map4[t] = make_int4(-1, -1, -1, -1);
    if (blockIdx.x == 0 && threadIdx.x < PNC) zrow[threadIdx.x] = 0.0f;
}

// Scatter pillar index p into map at its global cell. (Unique cells per
// problem setup -> no write races.)
__global__ void pp_scatter_map(const int4* __restrict__ coords,
                               int* __restrict__ map, int P) {
    int p = blockIdx.x * blockDim.x + threadIdx.x;
    if (p >= P) return;
    int4 c = coords[p];              // (b, z, y, x)
    int gidx = c.x * PLANE + c.y + c.z * PNX + c.w;
    map[gidx] = p;
}

// ---------------- gather ----------------
// One thread per cell. Branch-free: select the source row pointer (real
// pillar row or the shared zero row), then 16 unconditional f32x4 loads
// and 64 dword stores (each wave-store instruction = 256B contiguous).
__global__ void pp_gather(const float* __restrict__ feat,
                          const int* __restrict__ map,
                          const float* __restrict__ zrow,
                          float* __restrict__ out, int ncells) {
    int cell = blockIdx.x * blockDim.x + threadIdx.x;
    if (cell >= ncells) return;
    int b = cell / PLANE;
    int spat = cell - b * PLANE;
    int pm = map[cell];

    const float* src = (pm >= 0) ? (feat + (size_t)pm * PNC) : zrow;
    const f32x4* fp = reinterpret_cast<const f32x4*>(src);

    f32x4 r[16];
    #pragma unroll
    for (int g = 0; g < 16; ++g) r[g] = fp[g];

    float* o = out + (size_t)b * PNC * PLANE + spat;
    #pragma unroll
    for (int g = 0; g < 16; ++g) {
        o[(size_t)(4 * g + 0) * PLANE] = r[g].x;
        o[(size_t)(4 * g + 1) * PLANE] = r[g].y;
        o[(size_t)(4 * g + 2) * PLANE] = r[g].z;
        o[(size_t)(4 * g + 3) * PLANE] = r[g].w;
    }
}

// ---------------- fallback path (ws too small) ----------------

__global__ void pp_zero_out(f32x4* __restrict__ out4, size_t n4) {
    size_t t = (size_t)blockIdx.x * blockDim.x + threadIdx.x;
    size_t stride = (size_t)gridDim.x * blockDim.x;
    const f32x4 z = {0.f, 0.f, 0.f, 0.f};
    for (size_t i = t; i < n4; i += stride) out4[i] = z;
}

__global__ void pp_scatter_direct(const float* __restrict__ feat,
                                  const int4* __restrict__ coords,
                                  float* __restrict__ out, int P) {
    int t = blockIdx.x * blockDim.x + threadIdx.x;
    int p = t >> 6;
    int c = t & 63;
    if (p >= P) return;
    int4 co = coords[p];
    size_t oidx = ((size_t)(co.x * PNC + c)) * PLANE + co.y + co.z * PNX + co.w;
    out[oidx] = feat[p * PNC + c];
}

extern "C" void kernel_launch(void* const* d_in, const int* in_sizes, int n_in,
                              void* d_out, int out_size, void* d_ws, size_t ws_size,
                              hipStream_t stream) {
    const float* feat = (const float*)d_in[0];
    const int4* coords = (const int4*)d_in[1];
    float* out = (float*)d_out;

    const int P = in_sizes[0] / PNC;                 // 64000
    const int B = out_size / (PNC * PLANE);          // 4
    const int ncells = B * PLANE;                    // 857088
    const size_t mapBytes = (size_t)ncells * sizeof(int);   // 16B-aligned
    const size_t needBytes = mapBytes + PNC * sizeof(float);

    if (ws_size >= needBytes) {
        int* map = (int*)d_ws;
        float* zrow = (float*)((char*)d_ws + mapBytes);
        int n4 = ncells / 4;                         // 214272
        pp_init<<<(n4 + 255) / 256, 256, 0, stream>>>((int4*)map, zrow, n4);
        pp_scatter_map<<<(P + 255) / 256, 256, 0, stream>>>(coords, map, P);
        pp_gather<<<(ncells + 255) / 256, 256, 0, stream>>>(feat, map, zrow, out, ncells);
    } else {
        // Fallback: zero-fill + direct scatter (correct but more HBM traffic)
        size_t n4 = (size_t)out_size / 4;
        pp_zero_out<<<2048, 256, 0, stream>>>((f32x4*)out, n4);
        int total = P * PNC;
        pp_scatter_direct<<<(total + 255) / 256, 256, 0, stream>>>(feat, coords, out, P);
    }
}